// Round 1
// baseline (160.097 us; speedup 1.0000x reference)
//
#include <hip/hip_runtime.h>
#include <hip/hip_bf16.h>

typedef __attribute__((ext_vector_type(8))) short bf16x8;
typedef __attribute__((ext_vector_type(4))) float f32x4;

#define NTOK 49
#define CDIM 128
#define NHEAD 4
#define NWIN 64

__device__ __forceinline__ short f2b(float v) {
    __hip_bfloat16 b = __float2bfloat16(v);
    return *reinterpret_cast<short*>(&b);
}

__global__ void prep_kernel(const float* __restrict__ qkv_w,
                            const float* __restrict__ proj_w,
                            const float* __restrict__ rel_tab,
                            const int*   __restrict__ rel_idx,
                            short* __restrict__ wqkv_t,
                            short* __restrict__ wproj_t,
                            float* __restrict__ biasM) {
    int i = blockIdx.x * 256 + threadIdx.x;
    if (i < 384 * 128) {               // wqkv_t[n][k] = qkv_w[k][n]
        int n = i >> 7, k = i & 127;
        wqkv_t[i] = f2b(qkv_w[k * 384 + n]);
        return;
    }
    int j = i - 384 * 128;
    if (j < 128 * 128) {               // wproj_t[n][k] = proj_w[k][n]
        int n = j >> 7, k = j & 127;
        wproj_t[j] = f2b(proj_w[k * 128 + n]);
        return;
    }
    int l = j - 128 * 128;
    if (l < NHEAD * NTOK * NTOK) {     // biasM[h][i][j] = tab[rel_idx[i][j]][h]
        int h = l / (NTOK * NTOK);
        int rem = l - h * (NTOK * NTOK);
        biasM[l] = rel_tab[rel_idx[rem] * NHEAD + h];
    }
}

__launch_bounds__(256, 2)
__global__ void swin_fused(const float* __restrict__ x,
                           const short* __restrict__ wqkv_t,
                           const float* __restrict__ qkv_b,
                           const short* __restrict__ wproj_t,
                           const float* __restrict__ proj_b,
                           const float* __restrict__ biasM,
                           const float* __restrict__ mask,
                           float* __restrict__ out) {
    // padded rows: 136 shorts = 272B (16B aligned, bank-friendly)
    __shared__ short xb[NTOK][136];              // x tile, reused for attn-out
    __shared__ short qb[NTOK][136];
    __shared__ short kb[NTOK][136];
    __shared__ short vb[NTOK][136];
    __shared__ short pbuf[NHEAD][NTOK][72];      // P (softmax probs), bf16

    const int b   = blockIdx.x;
    const int tid = threadIdx.x;
    const int wv  = tid >> 6;       // wave id = head id
    const int ln  = tid & 63;
    const int g   = ln >> 4;        // 0..3
    const int c   = ln & 15;        // 0..15

    // ---------- load x tile (49x128 f32) -> bf16 LDS ----------
    const float* xp = x + (size_t)b * (NTOK * CDIM);
    for (int idx = tid; idx < NTOK * CDIM; idx += 256) {
        xb[idx >> 7][idx & 127] = f2b(xp[idx]);
    }
    __syncthreads();

    // ---------- QKV GEMM: M=49(pad64) N=384 K=128; wave wv -> cols [96wv,96wv+96) ----------
    {
        f32x4 acc[4][6];
        #pragma unroll
        for (int mt = 0; mt < 4; ++mt)
            #pragma unroll
            for (int nt = 0; nt < 6; ++nt) acc[mt][nt] = (f32x4){0.f, 0.f, 0.f, 0.f};
        #pragma unroll
        for (int kt = 0; kt < 4; ++kt) {
            bf16x8 afr[4];
            #pragma unroll
            for (int mt = 0; mt < 4; ++mt) {
                int row = 16 * mt + c; if (row > 48) row = 48;
                afr[mt] = *(const bf16x8*)&xb[row][kt * 32 + g * 8];
            }
            #pragma unroll
            for (int nt = 0; nt < 6; ++nt) {
                int n = 96 * wv + 16 * nt + c;
                bf16x8 bfr = *(const bf16x8*)&wqkv_t[n * CDIM + kt * 32 + g * 8];
                #pragma unroll
                for (int mt = 0; mt < 4; ++mt)
                    acc[mt][nt] = __builtin_amdgcn_mfma_f32_16x16x32_bf16(afr[mt], bfr, acc[mt][nt], 0, 0, 0);
            }
        }
        #pragma unroll
        for (int nt = 0; nt < 6; ++nt) {
            int n = 96 * wv + 16 * nt + c;
            float bias = qkv_b[n];
            short* dst; int nc;
            if (n < 128)      { dst = &qb[0][0]; nc = n; }
            else if (n < 256) { dst = &kb[0][0]; nc = n - 128; }
            else              { dst = &vb[0][0]; nc = n - 256; }
            #pragma unroll
            for (int mt = 0; mt < 4; ++mt)
                #pragma unroll
                for (int r = 0; r < 4; ++r) {
                    int row = 16 * mt + 4 * g + r;
                    if (row < NTOK) dst[row * 136 + nc] = f2b(acc[mt][nt][r] + bias);
                }
        }
    }
    __syncthreads();

    // ---------- attention: wave handles head h ----------
    const int h = wv;
    {
        // S = q_h (49x32) @ k_h^T -> 49x49 (pad 64x64); K=32 single step
        f32x4 s[4][4];
        #pragma unroll
        for (int mt = 0; mt < 4; ++mt)
            #pragma unroll
            for (int nt = 0; nt < 4; ++nt) s[mt][nt] = (f32x4){0.f, 0.f, 0.f, 0.f};
        bf16x8 aq[4];
        #pragma unroll
        for (int mt = 0; mt < 4; ++mt) {
            int row = 16 * mt + c; if (row > 48) row = 48;
            aq[mt] = *(const bf16x8*)&qb[row][h * 32 + g * 8];
        }
        #pragma unroll
        for (int nt = 0; nt < 4; ++nt) {
            int tok = 16 * nt + c; if (tok > 48) tok = 48;
            bf16x8 bk = *(const bf16x8*)&kb[tok][h * 32 + g * 8];
            #pragma unroll
            for (int mt = 0; mt < 4; ++mt)
                s[mt][nt] = __builtin_amdgcn_mfma_f32_16x16x32_bf16(aq[mt], bk, s[mt][nt], 0, 0, 0);
        }

        // softmax (C layout: row = 16mt+4g+r, col = 16nt+c); row spread over 16 lanes
        const float scale = 0.17677669529663687f;  // 32^-0.5
        const float* maskp = mask + (size_t)(b & (NWIN - 1)) * (NTOK * NTOK);
        const float* biasp = biasM + (size_t)h * (NTOK * NTOK);
        #pragma unroll
        for (int mt = 0; mt < 4; ++mt) {
            #pragma unroll
            for (int r = 0; r < 4; ++r) {
                int row = 16 * mt + 4 * g + r;
                int rowc = row > 48 ? 48 : row;
                float e[4];
                float mx = -1e30f;
                #pragma unroll
                for (int nt = 0; nt < 4; ++nt) {
                    int col = 16 * nt + c;
                    float v;
                    if (col < NTOK)
                        v = s[mt][nt][r] * scale + biasp[rowc * NTOK + col] + maskp[rowc * NTOK + col];
                    else
                        v = -1e30f;
                    e[nt] = v;
                    mx = fmaxf(mx, v);
                }
                #pragma unroll
                for (int off = 8; off >= 1; off >>= 1) mx = fmaxf(mx, __shfl_xor(mx, off, 64));
                float sum = 0.f;
                #pragma unroll
                for (int nt = 0; nt < 4; ++nt) { e[nt] = __expf(e[nt] - mx); sum += e[nt]; }
                #pragma unroll
                for (int off = 8; off >= 1; off >>= 1) sum += __shfl_xor(sum, off, 64);
                float rs = 1.0f / sum;
                if (row < NTOK) {
                    #pragma unroll
                    for (int nt = 0; nt < 4; ++nt)
                        pbuf[h][row][16 * nt + c] = f2b(e[nt] * rs);   // cols>=49 get 0
                }
            }
        }

        // PV: out_h = P(49x64pad) @ V_h(64x32); K pad cols of P are zero -> exact
        f32x4 o[4][2];
        #pragma unroll
        for (int mt = 0; mt < 4; ++mt) { o[mt][0] = (f32x4){0.f,0.f,0.f,0.f}; o[mt][1] = (f32x4){0.f,0.f,0.f,0.f}; }
        #pragma unroll
        for (int kt = 0; kt < 2; ++kt) {
            bf16x8 ap[4];
            #pragma unroll
            for (int mt = 0; mt < 4; ++mt) {
                int row = 16 * mt + c; if (row > 48) row = 48;
                ap[mt] = *(const bf16x8*)&pbuf[h][row][kt * 32 + g * 8];
            }
            #pragma unroll
            for (int nt = 0; nt < 2; ++nt) {
                bf16x8 bv;
                #pragma unroll
                for (int i = 0; i < 8; ++i) {
                    int t = kt * 32 + g * 8 + i; if (t > 48) t = 48;  // P is 0 there anyway
                    bv[i] = vb[t][h * 32 + 16 * nt + c];
                }
                #pragma unroll
                for (int mt = 0; mt < 4; ++mt)
                    o[mt][nt] = __builtin_amdgcn_mfma_f32_16x16x32_bf16(ap[mt], bv, o[mt][nt], 0, 0, 0);
            }
        }
        // attn-out (49x128) -> reuse xb
        #pragma unroll
        for (int nt = 0; nt < 2; ++nt)
            #pragma unroll
            for (int mt = 0; mt < 4; ++mt)
                #pragma unroll
                for (int r = 0; r < 4; ++r) {
                    int row = 16 * mt + 4 * g + r;
                    if (row < NTOK) xb[row][h * 32 + 16 * nt + c] = f2b(o[mt][nt][r]);
                }
    }
    __syncthreads();

    // ---------- proj GEMM: M=49 N=128 K=128; wave wv -> cols [32wv, 32wv+32) ----------
    {
        f32x4 acc[4][2];
        #pragma unroll
        for (int mt = 0; mt < 4; ++mt) { acc[mt][0] = (f32x4){0.f,0.f,0.f,0.f}; acc[mt][1] = (f32x4){0.f,0.f,0.f,0.f}; }
        #pragma unroll
        for (int kt = 0; kt < 4; ++kt) {
            bf16x8 afr[4];
            #pragma unroll
            for (int mt = 0; mt < 4; ++mt) {
                int row = 16 * mt + c; if (row > 48) row = 48;
                afr[mt] = *(const bf16x8*)&xb[row][kt * 32 + g * 8];
            }
            #pragma unroll
            for (int nt = 0; nt < 2; ++nt) {
                int n = 32 * wv + 16 * nt + c;
                bf16x8 bfr = *(const bf16x8*)&wproj_t[n * CDIM + kt * 32 + g * 8];
                #pragma unroll
                for (int mt = 0; mt < 4; ++mt)
                    acc[mt][nt] = __builtin_amdgcn_mfma_f32_16x16x32_bf16(afr[mt], bfr, acc[mt][nt], 0, 0, 0);
            }
        }
        float* op = out + (size_t)b * (NTOK * CDIM);
        #pragma unroll
        for (int nt = 0; nt < 2; ++nt) {
            int n = 32 * wv + 16 * nt + c;
            float bias = proj_b[n];
            #pragma unroll
            for (int mt = 0; mt < 4; ++mt)
                #pragma unroll
                for (int r = 0; r < 4; ++r) {
                    int row = 16 * mt + 4 * g + r;
                    if (row < NTOK) op[row * CDIM + n] = acc[mt][nt][r] + bias;
                }
        }
    }
}

extern "C" void kernel_launch(void* const* d_in, const int* in_sizes, int n_in,
                              void* d_out, int out_size, void* d_ws, size_t ws_size,
                              hipStream_t stream) {
    const float* x       = (const float*)d_in[0];
    const float* qkv_w   = (const float*)d_in[1];
    const float* qkv_b   = (const float*)d_in[2];
    const float* proj_w  = (const float*)d_in[3];
    const float* proj_b  = (const float*)d_in[4];
    const float* rel_tab = (const float*)d_in[5];
    const float* mask    = (const float*)d_in[6];
    const int*   rel_idx = (const int*)d_in[7];

    char* ws = (char*)d_ws;
    short* wqkv_t  = (short*)ws;                        // 98304 B
    short* wproj_t = (short*)(ws + 98304);              // 32768 B
    float* biasM   = (float*)(ws + 98304 + 32768);      // 38416 B

    int total = 384 * 128 + 128 * 128 + NHEAD * NTOK * NTOK;
    prep_kernel<<<(total + 255) / 256, 256, 0, stream>>>(qkv_w, proj_w, rel_tab, rel_idx,
                                                         wqkv_t, wproj_t, biasM);

    int B_ = in_sizes[0] / (NTOK * CDIM);               // 4096
    swin_fused<<<B_, 256, 0, stream>>>(x, wqkv_t, qkv_b, wproj_t, proj_b, biasM, mask,
                                       (float*)d_out);
}

// Round 3
// 129.026 us; speedup vs baseline: 1.2408x; 1.2408x over previous
//
#include <hip/hip_runtime.h>
#include <hip/hip_bf16.h>

typedef __attribute__((ext_vector_type(8))) short bf16x8;
typedef __attribute__((ext_vector_type(4))) short s16x4;
typedef __attribute__((ext_vector_type(4))) float f32x4;

#define NTOK 49

__device__ __forceinline__ short f2b(float v) {
    __hip_bfloat16 b = __float2bfloat16(v);
    return *reinterpret_cast<short*>(&b);
}

// window region id (mask[w][i][j]==0 iff rid(i)==rid(j)); wh,ww in 0..7
// slices: [0,49) -> 0, [49,53) -> 1 (4 rows), [53,56) -> 2 (3 rows)
__device__ __forceinline__ int rid_of(int t, int wh, int ww) {
    int i = t / 7;
    int j = t - 7 * i;
    int rh = (wh == 7) ? ((i < 4) ? 1 : 2) : 0;
    int rw = (ww == 7) ? ((j < 4) ? 1 : 2) : 0;
    return rh * 3 + rw;
}

__global__ void prep_kernel(const float* __restrict__ qkv_w,
                            const float* __restrict__ proj_w,
                            const float* __restrict__ rel_tab,
                            const int*   __restrict__ rel_idx,
                            short* __restrict__ wqkv_t,
                            short* __restrict__ wproj_t,
                            float* __restrict__ bmp) {
    int i = blockIdx.x * 256 + threadIdx.x;
    if (i < 384 * 128) {               // wqkv_t[n][k] = qkv_w[k][n]
        int n = i >> 7, k = i & 127;
        wqkv_t[i] = f2b(qkv_w[k * 384 + n]);
        return;
    }
    int j = i - 384 * 128;
    if (j < 128 * 128) {               // wproj_t[n][k] = proj_w[k][n]
        int n = j >> 7, k = j & 127;
        wproj_t[j] = f2b(proj_w[k * 128 + n]);
        return;
    }
    int l = j - 128 * 128;
    if (l < 4 * NTOK * 64) {           // bmp[h][q][k64] = tab[rel_idx[q][k]][h], pad 0
        int h = l / (NTOK * 64);
        int rem = l - h * (NTOK * 64);
        int q = rem >> 6, kk = rem & 63;
        bmp[l] = (kk < NTOK) ? rel_tab[rel_idx[q * NTOK + kk] * 4 + h] : 0.0f;
    }
}

// LDS layout in shorts (63120 bytes total):
//  [0, 6664)      xb [49][136]   (phase1 input X), reused as ob [49][136] (O, phase3)
//  [6664, 22344)  per-head region at 6664 + h*3920:
//                   qbh_h [49][40] at +0, kbh_h [49][40] at +1960
//                   pbuf_h [49][72] overlays at +0 after QK^T (post-B3)
//  [22344, 31560) vbt: per-head V^T [32][72] at 22344 + h*2304  ([dim][tok], toks 49..63 zeroed)
#define XB_BASE   0
#define XB_STR    136
#define HREG_BASE 6664
#define HREG_SZ   3920
#define QB_STR    40
#define PB_STR    72
#define VBT_BASE  22344
#define VBT_SZ    2304
#define VBT_STR   72

__launch_bounds__(512, 4)
__global__ void swin_fused(const float* __restrict__ x,
                           const short* __restrict__ wqkv_t,
                           const float* __restrict__ qkv_b,
                           const short* __restrict__ wproj_t,
                           const float* __restrict__ proj_b,
                           const float* __restrict__ bmp,
                           float* __restrict__ out) {
    __shared__ short sm[31560];

    const int b   = blockIdx.x;
    const int tid = threadIdx.x;
    const int wv  = tid >> 6;       // 0..7
    const int ln  = tid & 63;
    const int g   = ln >> 4;        // 0..3
    const int c   = ln & 15;        // 0..15
    const int h    = wv >> 1;       // head 0..3
    const int half = wv & 1;        // 0..1

    short* qbh  = sm + HREG_BASE + h * HREG_SZ;          // [49][40]
    short* kbh  = qbh + NTOK * QB_STR;                   // [49][40]
    short* pbh  = qbh;                                   // [49][72] overlay
    short* vbt  = sm + VBT_BASE + h * VBT_SZ;            // [32][72]

    // ---------- phase 0: load x (49x128 f32) -> bf16 LDS ----------
    {
        const f32x4* xp4 = (const f32x4*)(x + (size_t)b * (NTOK * 128));
        for (int idx = tid; idx < NTOK * 32; idx += 512) {
            f32x4 v = xp4[idx];
            int e0 = idx * 4;
            int row = e0 >> 7, col = e0 & 127;
            s16x4 pk;
            pk[0] = f2b(v[0]); pk[1] = f2b(v[1]); pk[2] = f2b(v[2]); pk[3] = f2b(v[3]);
            *(s16x4*)&sm[XB_BASE + row * XB_STR + col] = pk;
        }
    }
    __syncthreads();   // B1

    // ---------- phase 1: QKV^T = W^T(384x128) @ X^T(128x49pad64) ----------
    // wave (h,half) computes 3 channel tiles: q/k/v channels [32h+16half, +16)
    {
        const int bases[3] = { 32*h + 16*half, 128 + 32*h + 16*half, 256 + 32*h + 16*half };
        f32x4 acc[3][4];
        #pragma unroll
        for (int t = 0; t < 3; ++t)
            #pragma unroll
            for (int nt = 0; nt < 4; ++nt) acc[t][nt] = (f32x4){0.f,0.f,0.f,0.f};
        #pragma unroll
        for (int kt = 0; kt < 4; ++kt) {
            bf16x8 aw[3];
            #pragma unroll
            for (int t = 0; t < 3; ++t)
                aw[t] = *(const bf16x8*)&wqkv_t[(bases[t] + c) * 128 + 32*kt + 8*g];
            bf16x8 xv[4];
            #pragma unroll
            for (int nt = 0; nt < 4; ++nt) {
                int tok = 16*nt + c; if (tok > 48) tok = 48;
                xv[nt] = *(const bf16x8*)&sm[XB_BASE + tok * XB_STR + 32*kt + 8*g];
            }
            #pragma unroll
            for (int t = 0; t < 3; ++t)
                #pragma unroll
                for (int nt = 0; nt < 4; ++nt)
                    acc[t][nt] = __builtin_amdgcn_mfma_f32_16x16x32_bf16(aw[t], xv[nt], acc[t][nt], 0, 0, 0);
        }
        // epilogue: rows = channels (4 consecutive per lane), col = token = c
        const float scale = 0.17677669529663687f;  // 32^-0.5, folded into q
        #pragma unroll
        for (int t = 0; t < 3; ++t) {
            f32x4 b4 = *(const f32x4*)&qkv_b[bases[t] + 4*g];
            #pragma unroll
            for (int nt = 0; nt < 4; ++nt) {
                int tok = 16*nt + c;
                if (tok >= NTOK) continue;
                float v0 = acc[t][nt][0] + b4[0];
                float v1 = acc[t][nt][1] + b4[1];
                float v2 = acc[t][nt][2] + b4[2];
                float v3 = acc[t][nt][3] + b4[3];
                if (t == 0) { v0 *= scale; v1 *= scale; v2 *= scale; v3 *= scale; }
                if (t < 2) {
                    s16x4 pk; pk[0]=f2b(v0); pk[1]=f2b(v1); pk[2]=f2b(v2); pk[3]=f2b(v3);
                    short* dst = (t == 0) ? qbh : kbh;
                    *(s16x4*)&dst[tok * QB_STR + 16*half + 4*g] = pk;
                } else {
                    int d0 = 16*half + 4*g;
                    vbt[(d0+0) * VBT_STR + tok] = f2b(v0);
                    vbt[(d0+1) * VBT_STR + tok] = f2b(v1);
                    vbt[(d0+2) * VBT_STR + tok] = f2b(v2);
                    vbt[(d0+3) * VBT_STR + tok] = f2b(v3);
                }
            }
        }
        // zero-fill V^T toks 49..63 for this wave's 16 dims
        for (int i2 = ln; i2 < 16 * 15; i2 += 64) {
            int d = 16*half + i2 / 15;
            int t = 49 + i2 % 15;
            vbt[d * VBT_STR + t] = 0;
        }
    }
    __syncthreads();   // B2: qkv in LDS; xb dead

    // ---------- phase 2: S^T = K(64x32) @ Q^T(32x64) ----------
    const int ntq0 = 2 * half;   // this wave's 2 qtok tiles
    f32x4 sA[4][2];
    {
        #pragma unroll
        for (int mt = 0; mt < 4; ++mt) { sA[mt][0] = (f32x4){0.f,0.f,0.f,0.f}; sA[mt][1] = (f32x4){0.f,0.f,0.f,0.f}; }
        bf16x8 ak[4];
        #pragma unroll
        for (int mt = 0; mt < 4; ++mt) {
            int kt2 = 16*mt + c; if (kt2 > 48) kt2 = 48;
            ak[mt] = *(const bf16x8*)&kbh[kt2 * QB_STR + 8*g];
        }
        #pragma unroll
        for (int jj = 0; jj < 2; ++jj) {
            int qt = 16*(ntq0+jj) + c; if (qt > 48) qt = 48;
            bf16x8 bq = *(const bf16x8*)&qbh[qt * QB_STR + 8*g];
            #pragma unroll
            for (int mt = 0; mt < 4; ++mt)
                sA[mt][jj] = __builtin_amdgcn_mfma_f32_16x16x32_bf16(ak[mt], bq, sA[mt][jj], 0, 0, 0);
        }
    }
    __syncthreads();   // B3: q/k fragments consumed; pbuf may overlay

    // ---------- softmax (on S^T: row=ktok=16mt+4g+r, col=qtok) ----------
    {
        const int wh = (b >> 3) & 7, ww = b & 7;
        const bool wmask = (wh == 7) || (ww == 7);
        int ridk[16];
        if (wmask) {
            #pragma unroll
            for (int mt = 0; mt < 4; ++mt)
                #pragma unroll
                for (int r = 0; r < 4; ++r) {
                    int ktok = 16*mt + 4*g + r;
                    ridk[4*mt+r] = rid_of(ktok < NTOK ? ktok : 48, wh, ww);
                }
        }
        #pragma unroll
        for (int jj = 0; jj < 2; ++jj) {
            int qtok = 16*(ntq0+jj) + c;
            int qtokc = qtok > 48 ? 48 : qtok;
            int ridq = wmask ? rid_of(qtokc, wh, ww) : 0;
            const float* bp = bmp + ((size_t)h * NTOK + qtokc) * 64;
            float e[16];
            float mx = -1e30f;
            #pragma unroll
            for (int mt = 0; mt < 4; ++mt) {
                f32x4 b4 = *(const f32x4*)&bp[16*mt + 4*g];
                #pragma unroll
                for (int r = 0; r < 4; ++r) {
                    int ktok = 16*mt + 4*g + r;
                    float v = sA[mt][jj][r] + b4[r];
                    bool ok = (ktok < NTOK) && (!wmask || (ridk[4*mt+r] == ridq));
                    v = ok ? v : -1e30f;
                    e[4*mt+r] = v;
                    mx = fmaxf(mx, v);
                }
            }
            mx = fmaxf(mx, __shfl_xor(mx, 16, 64));
            mx = fmaxf(mx, __shfl_xor(mx, 32, 64));
            float s = 0.f;
            #pragma unroll
            for (int ii = 0; ii < 16; ++ii) { float ev = __expf(e[ii] - mx); e[ii] = ev; s += ev; }
            s += __shfl_xor(s, 16, 64);
            s += __shfl_xor(s, 32, 64);
            float rs = 1.0f / s;
            if (qtok < NTOK) {
                #pragma unroll
                for (int mt = 0; mt < 4; ++mt) {
                    s16x4 pk;
                    pk[0] = f2b(e[4*mt+0] * rs);
                    pk[1] = f2b(e[4*mt+1] * rs);
                    pk[2] = f2b(e[4*mt+2] * rs);
                    pk[3] = f2b(e[4*mt+3] * rs);
                    *(s16x4*)&pbh[qtok * PB_STR + 16*mt + 4*g] = pk;
                }
            }
        }
    }

    // ---------- phase 3: O^T = V^T(32x64) @ P^T(64x49pad) ----------
    {
        f32x4 o[2][2];
        o[0][0]=(f32x4){0.f,0.f,0.f,0.f}; o[0][1]=(f32x4){0.f,0.f,0.f,0.f};
        o[1][0]=(f32x4){0.f,0.f,0.f,0.f}; o[1][1]=(f32x4){0.f,0.f,0.f,0.f};
        #pragma unroll
        for (int kt = 0; kt < 2; ++kt) {
            bf16x8 av[2];
            #pragma unroll
            for (int mt = 0; mt < 2; ++mt)
                av[mt] = *(const bf16x8*)&vbt[(16*mt + c) * VBT_STR + 32*kt + 8*g];
            #pragma unroll
            for (int jj = 0; jj < 2; ++jj) {
                int qt = 16*(ntq0+jj) + c; if (qt > 48) qt = 48;
                bf16x8 bp2 = *(const bf16x8*)&pbh[qt * PB_STR + 32*kt + 8*g];
                #pragma unroll
                for (int mt = 0; mt < 2; ++mt)
                    o[mt][jj] = __builtin_amdgcn_mfma_f32_16x16x32_bf16(av[mt], bp2, o[mt][jj], 0, 0, 0);
            }
        }
        // write O to ob[qtok][32h + dim] (rows=dims consecutive -> packed)
        #pragma unroll
        for (int jj = 0; jj < 2; ++jj) {
            int qtok = 16*(ntq0+jj) + c;
            if (qtok >= NTOK) continue;
            #pragma unroll
            for (int mt = 0; mt < 2; ++mt) {
                s16x4 pk;
                pk[0] = f2b(o[mt][jj][0]); pk[1] = f2b(o[mt][jj][1]);
                pk[2] = f2b(o[mt][jj][2]); pk[3] = f2b(o[mt][jj][3]);
                *(s16x4*)&sm[XB_BASE + qtok * XB_STR + 32*h + 16*mt + 4*g] = pk;
            }
        }
    }
    __syncthreads();   // B4: O complete

    // ---------- phase 4: Y^T = Wp^T(128x128) @ O^T(128x49pad) ----------
    {
        const int chb = 16 * wv;
        f32x4 po[4];
        #pragma unroll
        for (int j = 0; j < 4; ++j) po[j] = (f32x4){0.f,0.f,0.f,0.f};
        #pragma unroll
        for (int kt = 0; kt < 4; ++kt) {
            bf16x8 aw = *(const bf16x8*)&wproj_t[(chb + c) * 128 + 32*kt + 8*g];
            #pragma unroll
            for (int j = 0; j < 4; ++j) {
                int qt = 16*j + c; if (qt > 48) qt = 48;
                bf16x8 bo = *(const bf16x8*)&sm[XB_BASE + qt * XB_STR + 32*kt + 8*g];
                po[j] = __builtin_amdgcn_mfma_f32_16x16x32_bf16(aw, bo, po[j], 0, 0, 0);
            }
        }
        f32x4 pb4 = *(const f32x4*)&proj_b[chb + 4*g];
        float* op = out + (size_t)b * (NTOK * 128);
        #pragma unroll
        for (int j = 0; j < 4; ++j) {
            int qtok = 16*j + c;
            if (qtok >= NTOK) continue;
            f32x4 w;
            w[0] = po[j][0] + pb4[0]; w[1] = po[j][1] + pb4[1];
            w[2] = po[j][2] + pb4[2]; w[3] = po[j][3] + pb4[3];
            *(f32x4*)&op[qtok * 128 + chb + 4*g] = w;
        }
    }
}

extern "C" void kernel_launch(void* const* d_in, const int* in_sizes, int n_in,
                              void* d_out, int out_size, void* d_ws, size_t ws_size,
                              hipStream_t stream) {
    const float* x       = (const float*)d_in[0];
    const float* qkv_w   = (const float*)d_in[1];
    const float* qkv_b   = (const float*)d_in[2];
    const float* proj_w  = (const float*)d_in[3];
    const float* proj_b  = (const float*)d_in[4];
    const float* rel_tab = (const float*)d_in[5];
    const int*   rel_idx = (const int*)d_in[7];

    char* ws = (char*)d_ws;
    short* wqkv_t  = (short*)ws;                        // 98304 B
    short* wproj_t = (short*)(ws + 98304);              // 32768 B
    float* bmp     = (float*)(ws + 98304 + 32768);      // 4*49*64*4 = 50176 B

    int total = 384*128 + 128*128 + 4*NTOK*64;
    prep_kernel<<<(total + 255) / 256, 256, 0, stream>>>(qkv_w, proj_w, rel_tab, rel_idx,
                                                         wqkv_t, wproj_t, bmp);

    int B_ = in_sizes[0] / (NTOK * 128);                // 4096
    swin_fused<<<B_, 512, 0, stream>>>(x, wqkv_t, qkv_b, wproj_t, proj_b, bmp,
                                       (float*)d_out);
}